// Round 3
// baseline (430.358 us; speedup 1.0000x reference)
//
#include <hip/hip_runtime.h>

typedef __bf16 bf16;
typedef __bf16 bf16x8 __attribute__((ext_vector_type(8)));
typedef __bf16 bf16x4 __attribute__((ext_vector_type(4)));
typedef float f32x4 __attribute__((ext_vector_type(4)));

#define MFMA_BF16(A, B, C) __builtin_amdgcn_mfma_f32_16x16x32_bf16((A), (B), (C), 0, 0, 0)

#define EMB 1024
#define ODIM 2048
#define SEQ 2048
#define HEADS 16
#define HD 128

// ---------------- mask bit-pack: mask (1,S,S) int32 -> mb[q][kt] uint64 ----------------
__global__ __launch_bounds__(256) void build_maskbits_k(const int* __restrict__ mask,
                                                        unsigned long long* __restrict__ mb) {
  int w = blockIdx.x * 256 + threadIdx.x;  // 0..65535 : q*32 + chunk
  int q = w >> 5, c = w & 31;
  const int4* m4 = reinterpret_cast<const int4*>(mask + (size_t)q * SEQ + c * 64);
  unsigned long long bits = 0ull;
#pragma unroll
  for (int i = 0; i < 16; ++i) {
    int4 v = m4[i];
    if (v.x) bits |= 1ull << (i * 4 + 0);
    if (v.y) bits |= 1ull << (i * 4 + 1);
    if (v.z) bits |= 1ull << (i * 4 + 2);
    if (v.w) bits |= 1ull << (i * 4 + 3);
  }
  mb[w] = bits;
}

// ---------------- projection GEMM: out = relu(X (4096x1024) * W^T (2048x1024) + b)*oscale ----------------
// vmode==0: write bf16 to outN[row][col] (row-major 4096x2048)
// vmode==1: write bf16 transposed per head to outT[((n*16+h)*128+d)*2048 + s]
__global__ __launch_bounds__(256) void proj_gemm_k(const float* __restrict__ X,
                                                   const float* __restrict__ W,
                                                   const float* __restrict__ bias,
                                                   bf16* __restrict__ outN,
                                                   bf16* __restrict__ outT,
                                                   int vmode, float oscale) {
  __shared__ union {
    struct { bf16 A[128][40]; bf16 B[128][40]; } s;  // +8 pad: 2-way conflicts max (free)
    bf16 C[128][136];                                // transpose buffer (epilogue only)
  } sm;

  const int t = threadIdx.x;
  const int lane = t & 63;
  const int wid = t >> 6;
  const int wm = wid >> 1, wn = wid & 1;
  const int lr = lane & 15, lg = lane >> 4;
  const int m0 = blockIdx.y * 128;
  const int n0 = blockIdx.x * 128;
  const int sr = t >> 1, sh = (t & 1) * 16;  // staging: 2 threads per row, 16 f32 each

  const f32x4 fzero = {0.f, 0.f, 0.f, 0.f};
  f32x4 acc[4][4];
#pragma unroll
  for (int i = 0; i < 4; ++i)
#pragma unroll
    for (int j = 0; j < 4; ++j) acc[i][j] = fzero;

  const float* Xr = X + (size_t)(m0 + sr) * EMB + sh;
  const float* Wr = W + (size_t)(n0 + sr) * EMB + sh;

  // async-split staging: issue tile k+1 loads while MFMAing tile k
  float4 ar[4], br[4];
  {
    const float4* pa = reinterpret_cast<const float4*>(Xr);
    const float4* pb = reinterpret_cast<const float4*>(Wr);
#pragma unroll
    for (int i = 0; i < 4; ++i) { ar[i] = pa[i]; br[i] = pb[i]; }
  }

  for (int k0 = 0; k0 < EMB; k0 += 32) {
    {
      bf16x8 v0, v1, w0, w1;
      v0[0] = (bf16)ar[0].x; v0[1] = (bf16)ar[0].y; v0[2] = (bf16)ar[0].z; v0[3] = (bf16)ar[0].w;
      v0[4] = (bf16)ar[1].x; v0[5] = (bf16)ar[1].y; v0[6] = (bf16)ar[1].z; v0[7] = (bf16)ar[1].w;
      v1[0] = (bf16)ar[2].x; v1[1] = (bf16)ar[2].y; v1[2] = (bf16)ar[2].z; v1[3] = (bf16)ar[2].w;
      v1[4] = (bf16)ar[3].x; v1[5] = (bf16)ar[3].y; v1[6] = (bf16)ar[3].z; v1[7] = (bf16)ar[3].w;
      w0[0] = (bf16)br[0].x; w0[1] = (bf16)br[0].y; w0[2] = (bf16)br[0].z; w0[3] = (bf16)br[0].w;
      w0[4] = (bf16)br[1].x; w0[5] = (bf16)br[1].y; w0[6] = (bf16)br[1].z; w0[7] = (bf16)br[1].w;
      w1[0] = (bf16)br[2].x; w1[1] = (bf16)br[2].y; w1[2] = (bf16)br[2].z; w1[3] = (bf16)br[2].w;
      w1[4] = (bf16)br[3].x; w1[5] = (bf16)br[3].y; w1[6] = (bf16)br[3].z; w1[7] = (bf16)br[3].w;
      *(bf16x8*)&sm.s.A[sr][sh] = v0;
      *(bf16x8*)&sm.s.A[sr][sh + 8] = v1;
      *(bf16x8*)&sm.s.B[sr][sh] = w0;
      *(bf16x8*)&sm.s.B[sr][sh + 8] = w1;
    }
    __syncthreads();
    if (k0 + 32 < EMB) {
      const float4* pa = reinterpret_cast<const float4*>(Xr + k0 + 32);
      const float4* pb = reinterpret_cast<const float4*>(Wr + k0 + 32);
#pragma unroll
      for (int i = 0; i < 4; ++i) { ar[i] = pa[i]; br[i] = pb[i]; }
    }
    bf16x8 af[4], bfr[4];
#pragma unroll
    for (int i = 0; i < 4; ++i) af[i] = *(const bf16x8*)&sm.s.A[wm * 64 + i * 16 + lr][lg * 8];
#pragma unroll
    for (int i = 0; i < 4; ++i) bfr[i] = *(const bf16x8*)&sm.s.B[wn * 64 + i * 16 + lr][lg * 8];
#pragma unroll
    for (int mi = 0; mi < 4; ++mi)
#pragma unroll
      for (int ni = 0; ni < 4; ++ni)
        acc[mi][ni] = MFMA_BF16(af[mi], bfr[ni], acc[mi][ni]);
    __syncthreads();
  }

  float bv_[4];
#pragma unroll
  for (int ni = 0; ni < 4; ++ni) bv_[ni] = bias[n0 + wn * 64 + ni * 16 + lr];

  if (!vmode) {
#pragma unroll
    for (int mi = 0; mi < 4; ++mi)
#pragma unroll
      for (int ni = 0; ni < 4; ++ni)
#pragma unroll
        for (int j = 0; j < 4; ++j) {
          float v = fmaxf(acc[mi][ni][j] + bv_[ni], 0.f) * oscale;
          int row = m0 + wm * 64 + mi * 16 + lg * 4 + j;
          int col = n0 + wn * 64 + ni * 16 + lr;
          outN[(size_t)row * ODIM + col] = (bf16)v;
        }
  } else {
    // transpose tile through LDS, then coalesced row writes into Vt[n][h][d][s]
#pragma unroll
    for (int mi = 0; mi < 4; ++mi)
#pragma unroll
      for (int ni = 0; ni < 4; ++ni)
#pragma unroll
        for (int j = 0; j < 4; ++j) {
          float v = fmaxf(acc[mi][ni][j] + bv_[ni], 0.f) * oscale;
          int rit = wm * 64 + mi * 16 + lg * 4 + j;  // s within tile
          int cit = wn * 64 + ni * 16 + lr;          // d within tile
          sm.C[cit][rit] = (bf16)v;
        }
    __syncthreads();
    const int n = m0 >> 11;
    const int s0 = m0 & (SEQ - 1);
    const int h = blockIdx.x;  // n0/128 == head (BN==HD)
    bf16* base = outT + ((size_t)(n * HEADS + h) * HD) * SEQ + s0;
#pragma unroll
    for (int i = 0; i < 8; ++i) {
      int cid = i * 256 + t;
      int d = cid >> 4, c = cid & 15;
      *(bf16x8*)(base + (size_t)d * SEQ + c * 8) = *(const bf16x8*)&sm.C[d][c * 8];
    }
  }
}

// ---------------- flash attention v3: no K/V LDS staging, no barriers ----------------
// 1D grid of 512 blocks, XCD-swizzled (cpx=64 -> 4 heads per XCD's L2).
// 256 threads = 4 waves; 32 q-rows per wave (two 16-col B fragments), 128 q/block.
// K and V MFMA A-fragments are read DIRECTLY from global (L1/L2-resident planes).
// QK^T as mfma(K,Q) -> S^T (q on lane&15, lane-local softmax); PV as mfma(V^T,P) -> O^T.
__global__ __launch_bounds__(256) void attn_k(const bf16* __restrict__ Qb,
                                              const bf16* __restrict__ Kb,
                                              const bf16* __restrict__ Vt,
                                              const unsigned long long* __restrict__ mb,
                                              float* __restrict__ out) {
  __shared__ bf16 Ps[4][32][72];  // per-wave P: [q][k], +8 pad

  const int t = threadIdx.x;
  const int lane = t & 63;
  const int w = t >> 6;
  const int lr = lane & 15, lg = lane >> 4;

  const int bid = blockIdx.x;
  const int swz = (bid & 7) * 64 + (bid >> 3);  // bijective: 512 = 8 * 64
  const int nh = swz >> 4;
  const int qt = swz & 15;
  const int n = nh >> 4, h = nh & 15;
  const int qrow = qt * 128 + w * 32;

  // Q fragments (B-operand: col=q=lane&15, k=d). Q is pre-scaled by 1/sqrt(HD).
  bf16x8 qf[2][4];
#pragma unroll
  for (int g = 0; g < 2; ++g) {
    const bf16* qp = Qb + (size_t)(n * SEQ + qrow + g * 16 + lr) * ODIM + h * HD + lg * 8;
#pragma unroll
    for (int ks = 0; ks < 4; ++ks) qf[g][ks] = *(const bf16x8*)(qp + ks * 32);
  }

  // per-lane base pointers for direct fragment loads
  const bf16* Krow = Kb + (size_t)(n * SEQ + lr) * ODIM + h * HD + lg * 8;
  const bf16* Vrow = Vt + (size_t)(nh * HD + lr) * SEQ + lg * 8;

  const f32x4 fzero = {0.f, 0.f, 0.f, 0.f};
  f32x4 oacc[2][8];
#pragma unroll
  for (int g = 0; g < 2; ++g)
#pragma unroll
    for (int i = 0; i < 8; ++i) oacc[g][i] = fzero;
  float mrun[2] = {-3.0e38f, -3.0e38f}, lrun[2] = {0.f, 0.f};

  const float L2E = 1.4426950408889634f;

  for (int kt = 0; kt < SEQ / 64; ++kt) {
    unsigned long long mw0 = mb[(size_t)(qrow + lr) * 32 + kt];
    unsigned long long mw1 = mb[(size_t)(qrow + 16 + lr) * 32 + kt];

    // ---- S^T = K Q^T : direct global K fragment loads (row = key, 64B/row per lg-group) ----
    f32x4 sacc[2][4];
#pragma unroll
    for (int g = 0; g < 2; ++g)
#pragma unroll
      for (int f = 0; f < 4; ++f) sacc[g][f] = fzero;
#pragma unroll
    for (int f = 0; f < 4; ++f) {
      const bf16* kp = Krow + (size_t)(kt * 64 + f * 16) * ODIM;
#pragma unroll
      for (int ks = 0; ks < 4; ++ks) {
        bf16x8 kf = *(const bf16x8*)(kp + ks * 32);
        sacc[0][f] = MFMA_BF16(kf, qf[0][ks], sacc[0][f]);
        sacc[1][f] = MFMA_BF16(kf, qf[1][ks], sacc[1][f]);
      }
    }

    // ---- lane-local online softmax (k = f*16+lg*4+j, q = qrow+g*16+lr) ----
    float mt[2] = {-3.0e38f, -3.0e38f};
#pragma unroll
    for (int f = 0; f < 4; ++f)
#pragma unroll
      for (int j = 0; j < 4; ++j) {
        int kk = f * 16 + lg * 4 + j;
        float x0 = ((mw0 >> kk) & 1ull) ? sacc[0][f][j] : -1.0e7f;
        float x1 = ((mw1 >> kk) & 1ull) ? sacc[1][f][j] : -1.0e7f;
        sacc[0][f][j] = x0;
        sacc[1][f][j] = x1;
        mt[0] = fmaxf(mt[0], x0);
        mt[1] = fmaxf(mt[1], x1);
      }
#pragma unroll
    for (int g = 0; g < 2; ++g) {
      mt[g] = fmaxf(mt[g], __shfl_xor(mt[g], 16));
      mt[g] = fmaxf(mt[g], __shfl_xor(mt[g], 32));
    }

    // defer-max (T13): rescale only when max moved by >8
    if (!__all((mt[0] <= mrun[0] + 8.0f) && (mt[1] <= mrun[1] + 8.0f))) {
#pragma unroll
      for (int g = 0; g < 2; ++g) {
        float mnew = fmaxf(mrun[g], mt[g]);
        float alpha = exp2f((mrun[g] - mnew) * L2E);
        mrun[g] = mnew;
        lrun[g] *= alpha;
#pragma unroll
        for (int df = 0; df < 8; ++df)
#pragma unroll
          for (int j = 0; j < 4; ++j) oacc[g][df][j] *= alpha;
      }
    }

    // ---- P = exp(S - m), per-wave LDS redistribution ----
    float psum[2] = {0.f, 0.f};
#pragma unroll
    for (int g = 0; g < 2; ++g)
#pragma unroll
      for (int f = 0; f < 4; ++f) {
        bf16x4 pw;
#pragma unroll
        for (int j = 0; j < 4; ++j) {
          float p = exp2f((sacc[g][f][j] - mrun[g]) * L2E);
          psum[g] += p;
          pw[j] = (bf16)p;
        }
        *(bf16x4*)&Ps[w][g * 16 + lr][f * 16 + lg * 4] = pw;
      }
#pragma unroll
    for (int g = 0; g < 2; ++g) {
      psum[g] += __shfl_xor(psum[g], 16);
      psum[g] += __shfl_xor(psum[g], 32);
      lrun[g] += psum[g];
    }

    bf16x8 pB[2][2];
#pragma unroll
    for (int g = 0; g < 2; ++g)
#pragma unroll
      for (int ks = 0; ks < 2; ++ks)
        pB[g][ks] = *(const bf16x8*)&Ps[w][g * 16 + lr][ks * 32 + lg * 8];

    // ---- O^T += V^T P : direct global V fragment loads ----
#pragma unroll
    for (int df = 0; df < 8; ++df) {
      const bf16* vp = Vrow + (size_t)(df * 16) * SEQ + kt * 64;
#pragma unroll
      for (int ks = 0; ks < 2; ++ks) {
        bf16x8 vf = *(const bf16x8*)(vp + ks * 32);
        oacc[0][df] = MFMA_BF16(vf, pB[0][ks], oacc[0][df]);
        oacc[1][df] = MFMA_BF16(vf, pB[1][ks], oacc[1][df]);
      }
    }
  }

  // ---- epilogue: O /= l ; float4 stores ----
#pragma unroll
  for (int g = 0; g < 2; ++g) {
    float inv = 1.0f / lrun[g];
    float* obase = out + (size_t)(n * SEQ + qrow + g * 16 + lr) * ODIM + h * HD;
#pragma unroll
    for (int df = 0; df < 8; ++df) {
      f32x4 o;
#pragma unroll
      for (int j = 0; j < 4; ++j) o[j] = oacc[g][df][j] * inv;
      *(f32x4*)(obase + df * 16 + lg * 4) = o;
    }
  }
}

extern "C" void kernel_launch(void* const* d_in, const int* in_sizes, int n_in,
                              void* d_out, int out_size, void* d_ws, size_t ws_size,
                              hipStream_t stream) {
  const float* q   = (const float*)d_in[0];
  const float* k   = (const float*)d_in[1];
  const float* v   = (const float*)d_in[2];
  const int*  mask = (const int*)d_in[3];
  const float* Wq  = (const float*)d_in[4];
  const float* bq  = (const float*)d_in[5];
  const float* Wk  = (const float*)d_in[6];
  const float* bk  = (const float*)d_in[7];
  const float* Wv  = (const float*)d_in[8];
  const float* bv  = (const float*)d_in[9];
  float* out = (float*)d_out;

  char* ws = (char*)d_ws;
  const size_t PLANE = (size_t)4096 * 2048 * sizeof(bf16);  // 16 MiB
  bf16* Qb = (bf16*)ws;
  bf16* Kb = (bf16*)(ws + PLANE);
  bf16* Vt = (bf16*)(ws + 2 * PLANE);
  unsigned long long* mb = (unsigned long long*)(ws + 3 * PLANE);

  const float qscale = 0.08838834764831845f;  // 1/sqrt(128), folded into Q projection

  build_maskbits_k<<<256, 256, 0, stream>>>(mask, mb);
  proj_gemm_k<<<dim3(16, 32), 256, 0, stream>>>(q, Wq, bq, Qb, nullptr, 0, qscale);
  proj_gemm_k<<<dim3(16, 32), 256, 0, stream>>>(k, Wk, bk, Kb, nullptr, 0, 1.0f);
  proj_gemm_k<<<dim3(16, 32), 256, 0, stream>>>(v, Wv, bv, nullptr, Vt, 1, 1.0f);
  attn_k<<<512, 256, 0, stream>>>(Qb, Kb, Vt, mb, out);
}

// Round 4
// 231.877 us; speedup vs baseline: 1.8560x; 1.8560x over previous
//
#include <hip/hip_runtime.h>

typedef __bf16 bf16;
typedef __bf16 bf16x8 __attribute__((ext_vector_type(8)));
typedef __bf16 bf16x4 __attribute__((ext_vector_type(4)));
typedef float f32x4 __attribute__((ext_vector_type(4)));

#define MFMA_BF16(A, B, C) __builtin_amdgcn_mfma_f32_16x16x32_bf16((A), (B), (C), 0, 0, 0)

#define EMB 1024
#define ODIM 2048
#define SEQ 2048
#define HEADS 16
#define HD 128

// ---------------- mask bit-pack: mask (1,S,S) int32 -> mb[q][kt] uint64 ----------------
__global__ __launch_bounds__(256) void build_maskbits_k(const int* __restrict__ mask,
                                                        unsigned long long* __restrict__ mb) {
  int w = blockIdx.x * 256 + threadIdx.x;  // 0..65535 : q*32 + chunk
  int q = w >> 5, c = w & 31;
  const int4* m4 = reinterpret_cast<const int4*>(mask + (size_t)q * SEQ + c * 64);
  unsigned long long bits = 0ull;
#pragma unroll
  for (int i = 0; i < 16; ++i) {
    int4 v = m4[i];
    if (v.x) bits |= 1ull << (i * 4 + 0);
    if (v.y) bits |= 1ull << (i * 4 + 1);
    if (v.z) bits |= 1ull << (i * 4 + 2);
    if (v.w) bits |= 1ull << (i * 4 + 3);
  }
  mb[w] = bits;
}

// ---------------- projection GEMM: out = relu(X (4096x1024) * W^T (2048x1024) + b)*oscale ----------------
__global__ __launch_bounds__(256) void proj_gemm_k(const float* __restrict__ X,
                                                   const float* __restrict__ W,
                                                   const float* __restrict__ bias,
                                                   bf16* __restrict__ outN,
                                                   bf16* __restrict__ outT,
                                                   int vmode, float oscale) {
  __shared__ union {
    struct { bf16 A[128][40]; bf16 B[128][40]; } s;  // +8 pad: 2-way conflicts max (free)
    bf16 C[128][136];                                // transpose buffer (epilogue only)
  } sm;

  const int t = threadIdx.x;
  const int lane = t & 63;
  const int wid = t >> 6;
  const int wm = wid >> 1, wn = wid & 1;
  const int lr = lane & 15, lg = lane >> 4;
  const int m0 = blockIdx.y * 128;
  const int n0 = blockIdx.x * 128;
  const int sr = t >> 1, sh = (t & 1) * 16;  // staging: 2 threads per row, 16 f32 each

  const f32x4 fzero = {0.f, 0.f, 0.f, 0.f};
  f32x4 acc[4][4];
#pragma unroll
  for (int i = 0; i < 4; ++i)
#pragma unroll
    for (int j = 0; j < 4; ++j) acc[i][j] = fzero;

  const float* Xr = X + (size_t)(m0 + sr) * EMB + sh;
  const float* Wr = W + (size_t)(n0 + sr) * EMB + sh;

  // async-split staging: issue tile k+1 loads while MFMAing tile k
  float4 ar[4], br[4];
  {
    const float4* pa = reinterpret_cast<const float4*>(Xr);
    const float4* pb = reinterpret_cast<const float4*>(Wr);
#pragma unroll
    for (int i = 0; i < 4; ++i) { ar[i] = pa[i]; br[i] = pb[i]; }
  }

  for (int k0 = 0; k0 < EMB; k0 += 32) {
    {
      bf16x8 v0, v1, w0, w1;
      v0[0] = (bf16)ar[0].x; v0[1] = (bf16)ar[0].y; v0[2] = (bf16)ar[0].z; v0[3] = (bf16)ar[0].w;
      v0[4] = (bf16)ar[1].x; v0[5] = (bf16)ar[1].y; v0[6] = (bf16)ar[1].z; v0[7] = (bf16)ar[1].w;
      v1[0] = (bf16)ar[2].x; v1[1] = (bf16)ar[2].y; v1[2] = (bf16)ar[2].z; v1[3] = (bf16)ar[2].w;
      v1[4] = (bf16)ar[3].x; v1[5] = (bf16)ar[3].y; v1[6] = (bf16)ar[3].z; v1[7] = (bf16)ar[3].w;
      w0[0] = (bf16)br[0].x; w0[1] = (bf16)br[0].y; w0[2] = (bf16)br[0].z; w0[3] = (bf16)br[0].w;
      w0[4] = (bf16)br[1].x; w0[5] = (bf16)br[1].y; w0[6] = (bf16)br[1].z; w0[7] = (bf16)br[1].w;
      w1[0] = (bf16)br[2].x; w1[1] = (bf16)br[2].y; w1[2] = (bf16)br[2].z; w1[3] = (bf16)br[2].w;
      w1[4] = (bf16)br[3].x; w1[5] = (bf16)br[3].y; w1[6] = (bf16)br[3].z; w1[7] = (bf16)br[3].w;
      *(bf16x8*)&sm.s.A[sr][sh] = v0;
      *(bf16x8*)&sm.s.A[sr][sh + 8] = v1;
      *(bf16x8*)&sm.s.B[sr][sh] = w0;
      *(bf16x8*)&sm.s.B[sr][sh + 8] = w1;
    }
    __syncthreads();
    if (k0 + 32 < EMB) {
      const float4* pa = reinterpret_cast<const float4*>(Xr + k0 + 32);
      const float4* pb = reinterpret_cast<const float4*>(Wr + k0 + 32);
#pragma unroll
      for (int i = 0; i < 4; ++i) { ar[i] = pa[i]; br[i] = pb[i]; }
    }
    bf16x8 af[4], bfr[4];
#pragma unroll
    for (int i = 0; i < 4; ++i) af[i] = *(const bf16x8*)&sm.s.A[wm * 64 + i * 16 + lr][lg * 8];
#pragma unroll
    for (int i = 0; i < 4; ++i) bfr[i] = *(const bf16x8*)&sm.s.B[wn * 64 + i * 16 + lr][lg * 8];
#pragma unroll
    for (int mi = 0; mi < 4; ++mi)
#pragma unroll
      for (int ni = 0; ni < 4; ++ni)
        acc[mi][ni] = MFMA_BF16(af[mi], bfr[ni], acc[mi][ni]);
    __syncthreads();
  }

  float bv_[4];
#pragma unroll
  for (int ni = 0; ni < 4; ++ni) bv_[ni] = bias[n0 + wn * 64 + ni * 16 + lr];

  if (!vmode) {
#pragma unroll
    for (int mi = 0; mi < 4; ++mi)
#pragma unroll
      for (int ni = 0; ni < 4; ++ni)
#pragma unroll
        for (int j = 0; j < 4; ++j) {
          float v = fmaxf(acc[mi][ni][j] + bv_[ni], 0.f) * oscale;
          int row = m0 + wm * 64 + mi * 16 + lg * 4 + j;
          int col = n0 + wn * 64 + ni * 16 + lr;
          outN[(size_t)row * ODIM + col] = (bf16)v;
        }
  } else {
    // transpose tile through LDS, then coalesced row writes into Vt[n][h][d][s]
#pragma unroll
    for (int mi = 0; mi < 4; ++mi)
#pragma unroll
      for (int ni = 0; ni < 4; ++ni)
#pragma unroll
        for (int j = 0; j < 4; ++j) {
          float v = fmaxf(acc[mi][ni][j] + bv_[ni], 0.f) * oscale;
          int rit = wm * 64 + mi * 16 + lg * 4 + j;  // s within tile
          int cit = wn * 64 + ni * 16 + lr;          // d within tile
          sm.C[cit][rit] = (bf16)v;
        }
    __syncthreads();
    const int n = m0 >> 11;
    const int s0 = m0 & (SEQ - 1);
    const int h = blockIdx.x;  // n0/128 == head (BN==HD)
    bf16* base = outT + ((size_t)(n * HEADS + h) * HD) * SEQ + s0;
#pragma unroll
    for (int i = 0; i < 8; ++i) {
      int cid = i * 256 + t;
      int d = cid >> 4, c = cid & 15;
      *(bf16x8*)(base + (size_t)d * SEQ + c * 8) = *(const bf16x8*)&sm.C[d][c * 8];
    }
  }
}

// ---------------- flash attention v4: LDS-staged + T2 XOR swizzle + 32 q/wave ----------------
// grid: 512 blocks XCD-swizzled; 256 threads = 4 waves; 32 q-rows/wave (two 16-col B frags).
// QK^T as mfma(K,Q) -> S^T (q on lane&15, lane-local softmax); PV as mfma(V^T,P) -> O^T.
// Ks/Vs linear tiles with byte ^= (row&7)<<4 swizzle on BOTH write and read (T2).

__device__ __forceinline__ int kswz(int r, int c) {  // bf16 index into Ks[64][128]
  int b = (r << 8) | (c << 1);
  b ^= (r & 7) << 4;
  return b >> 1;
}
__device__ __forceinline__ int vswz(int d, int s) {  // bf16 index into Vs[128][64]
  int b = (d << 7) | (s << 1);
  b ^= (d & 7) << 4;
  return b >> 1;
}

__global__ __launch_bounds__(256, 2) void attn_k(const bf16* __restrict__ Qb,
                                                 const bf16* __restrict__ Kb,
                                                 const bf16* __restrict__ Vt,
                                                 const unsigned long long* __restrict__ mb,
                                                 float* __restrict__ out) {
  __shared__ bf16 Ks[64 * 128];   // swizzled, 16 KB
  __shared__ bf16 Vs[128 * 64];   // swizzled, 16 KB
  __shared__ bf16 Ps[4][32][72];  // per-wave P: [q][k], +8 pad, 18 KB

  const int t = threadIdx.x;
  const int lane = t & 63;
  const int w = t >> 6;
  const int lr = lane & 15, lg = lane >> 4;

  const int bid = blockIdx.x;
  const int swz = (bid & 7) * 64 + (bid >> 3);  // bijective: 512 = 8*64; 4 heads per XCD
  const int nh = swz >> 4;
  const int qt = swz & 15;
  const int n = nh >> 4, h = nh & 15;
  const int qrow = qt * 128 + w * 32;

  // Q fragments (B-operand: col=q=lane&15, k=d). Q is pre-scaled by 1/sqrt(HD).
  bf16x8 qf[2][4];
#pragma unroll
  for (int g = 0; g < 2; ++g) {
    const bf16* qp = Qb + (size_t)(n * SEQ + qrow + g * 16 + lr) * ODIM + h * HD + lg * 8;
#pragma unroll
    for (int ks = 0; ks < 4; ++ks) qf[g][ks] = *(const bf16x8*)(qp + ks * 32);
  }

  const bf16* Kg = Kb + (size_t)(n * SEQ) * ODIM + h * HD;
  const bf16* Vg = Vt + (size_t)nh * HD * SEQ;

  // staging assignments (reg-staged, async-split)
  const int rK = t >> 4, cK = t & 15;  // K: 16 threads/row, 8 bf16 each
  const int dV = t >> 3, cV = t & 7;   // V^T: 8 threads/row
  const bf16* kgp = Kg + (size_t)rK * ODIM + cK * 8;
  const bf16* vgp = Vg + (size_t)dV * SEQ + cV * 8;

  bf16x8 kreg[4], vreg[4];
#pragma unroll
  for (int i = 0; i < 4; ++i) kreg[i] = *(const bf16x8*)(kgp + (size_t)i * 16 * ODIM);
#pragma unroll
  for (int i = 0; i < 4; ++i) vreg[i] = *(const bf16x8*)(vgp + (size_t)i * 32 * SEQ);

  const f32x4 fzero = {0.f, 0.f, 0.f, 0.f};
  f32x4 oacc[2][8];  // O^T frags: oacc[g][df][j] = O[d=df*16+lg*4+j][q=qrow+g*16+lr]
#pragma unroll
  for (int g = 0; g < 2; ++g)
#pragma unroll
    for (int i = 0; i < 8; ++i) oacc[g][i] = fzero;
  float mrun[2] = {-3.0e38f, -3.0e38f}, lrun[2] = {0.f, 0.f};

  const float L2E = 1.4426950408889634f;

  for (int kt = 0; kt < SEQ / 64; ++kt) {
    // ---- write staged regs (tile kt) to swizzled LDS ----
#pragma unroll
    for (int i = 0; i < 4; ++i) *(bf16x8*)&Ks[kswz(rK + i * 16, cK * 8)] = kreg[i];
#pragma unroll
    for (int i = 0; i < 4; ++i) *(bf16x8*)&Vs[vswz(dV + i * 32, cV * 8)] = vreg[i];
    __syncthreads();

    // ---- issue tile kt+1 global loads (latency hides under compute below) ----
    if (kt + 1 < SEQ / 64) {
      const bf16* kn = kgp + (size_t)(kt + 1) * 64 * ODIM;
      const bf16* vn = vgp + (size_t)(kt + 1) * 64;
#pragma unroll
      for (int i = 0; i < 4; ++i) kreg[i] = *(const bf16x8*)(kn + (size_t)i * 16 * ODIM);
#pragma unroll
      for (int i = 0; i < 4; ++i) vreg[i] = *(const bf16x8*)(vn + (size_t)i * 32 * SEQ);
    }

    unsigned long long mw0 = mb[(size_t)(qrow + lr) * 32 + kt];
    unsigned long long mw1 = mb[(size_t)(qrow + 16 + lr) * 32 + kt];

    // ---- S^T = K Q^T : each K frag feeds both q-groups ----
    f32x4 sacc[2][4];
#pragma unroll
    for (int g = 0; g < 2; ++g)
#pragma unroll
      for (int f = 0; f < 4; ++f) sacc[g][f] = fzero;
#pragma unroll
    for (int f = 0; f < 4; ++f) {
#pragma unroll
      for (int ks = 0; ks < 4; ++ks) {
        bf16x8 kf = *(const bf16x8*)&Ks[kswz(f * 16 + lr, ks * 32 + lg * 8)];
        sacc[0][f] = MFMA_BF16(kf, qf[0][ks], sacc[0][f]);
        sacc[1][f] = MFMA_BF16(kf, qf[1][ks], sacc[1][f]);
      }
    }

    // ---- lane-local online softmax (k = f*16+lg*4+j, q = qrow+g*16+lr) ----
    float mt[2] = {-3.0e38f, -3.0e38f};
#pragma unroll
    for (int f = 0; f < 4; ++f)
#pragma unroll
      for (int j = 0; j < 4; ++j) {
        int kk = f * 16 + lg * 4 + j;
        float x0 = ((mw0 >> kk) & 1ull) ? sacc[0][f][j] : -1.0e7f;
        float x1 = ((mw1 >> kk) & 1ull) ? sacc[1][f][j] : -1.0e7f;
        sacc[0][f][j] = x0;
        sacc[1][f][j] = x1;
        mt[0] = fmaxf(mt[0], x0);
        mt[1] = fmaxf(mt[1], x1);
      }
#pragma unroll
    for (int g = 0; g < 2; ++g) {
      mt[g] = fmaxf(mt[g], __shfl_xor(mt[g], 16));
      mt[g] = fmaxf(mt[g], __shfl_xor(mt[g], 32));
    }

    // defer-max (T13): rescale only when max moved by >8
    if (!__all((mt[0] <= mrun[0] + 8.0f) && (mt[1] <= mrun[1] + 8.0f))) {
#pragma unroll
      for (int g = 0; g < 2; ++g) {
        float mnew = fmaxf(mrun[g], mt[g]);
        float alpha = exp2f((mrun[g] - mnew) * L2E);
        mrun[g] = mnew;
        lrun[g] *= alpha;
#pragma unroll
        for (int df = 0; df < 8; ++df)
#pragma unroll
          for (int j = 0; j < 4; ++j) oacc[g][df][j] *= alpha;
      }
    }

    // ---- P = exp(S - m), per-wave LDS redistribution ----
    float psum[2] = {0.f, 0.f};
#pragma unroll
    for (int g = 0; g < 2; ++g)
#pragma unroll
      for (int f = 0; f < 4; ++f) {
        bf16x4 pw;
#pragma unroll
        for (int j = 0; j < 4; ++j) {
          float p = exp2f((sacc[g][f][j] - mrun[g]) * L2E);
          psum[g] += p;
          pw[j] = (bf16)p;
        }
        *(bf16x4*)&Ps[w][g * 16 + lr][f * 16 + lg * 4] = pw;
      }
#pragma unroll
    for (int g = 0; g < 2; ++g) {
      psum[g] += __shfl_xor(psum[g], 16);
      psum[g] += __shfl_xor(psum[g], 32);
      lrun[g] += psum[g];
    }

    bf16x8 pB[2][2];
#pragma unroll
    for (int g = 0; g < 2; ++g)
#pragma unroll
      for (int ks = 0; ks < 2; ++ks)
        pB[g][ks] = *(const bf16x8*)&Ps[w][g * 16 + lr][ks * 32 + lg * 8];

    // ---- O^T += V^T P : each V frag feeds both q-groups ----
#pragma unroll
    for (int df = 0; df < 8; ++df) {
#pragma unroll
      for (int ks = 0; ks < 2; ++ks) {
        bf16x8 vf = *(const bf16x8*)&Vs[vswz(df * 16 + lr, ks * 32 + lg * 8)];
        oacc[0][df] = MFMA_BF16(vf, pB[0][ks], oacc[0][df]);
        oacc[1][df] = MFMA_BF16(vf, pB[1][ks], oacc[1][df]);
      }
    }
    __syncthreads();
  }

  // ---- epilogue: O /= l ; float4 stores ----
#pragma unroll
  for (int g = 0; g < 2; ++g) {
    float inv = 1.0f / lrun[g];
    float* obase = out + (size_t)(n * SEQ + qrow + g * 16 + lr) * ODIM + h * HD;
#pragma unroll
    for (int df = 0; df < 8; ++df) {
      f32x4 o;
#pragma unroll
      for (int j = 0; j < 4; ++j) o[j] = oacc[g][df][j] * inv;
      *(f32x4*)(obase + df * 16 + lg * 4) = o;
    }
  }
}

extern "C" void kernel_launch(void* const* d_in, const int* in_sizes, int n_in,
                              void* d_out, int out_size, void* d_ws, size_t ws_size,
                              hipStream_t stream) {
  const float* q   = (const float*)d_in[0];
  const float* k   = (const float*)d_in[1];
  const float* v   = (const float*)d_in[2];
  const int*  mask = (const int*)d_in[3];
  const float* Wq  = (const float*)d_in[4];
  const float* bq  = (const float*)d_in[5];
  const float* Wk  = (const float*)d_in[6];
  const float* bk  = (const float*)d_in[7];
  const float* Wv  = (const float*)d_in[8];
  const float* bv  = (const float*)d_in[9];
  float* out = (float*)d_out;

  char* ws = (char*)d_ws;
  const size_t PLANE = (size_t)4096 * 2048 * sizeof(bf16);  // 16 MiB
  bf16* Qb = (bf16*)ws;
  bf16* Kb = (bf16*)(ws + PLANE);
  bf16* Vt = (bf16*)(ws + 2 * PLANE);
  unsigned long long* mb = (unsigned long long*)(ws + 3 * PLANE);

  const float qscale = 0.08838834764831845f;  // 1/sqrt(128), folded into Q projection

  build_maskbits_k<<<256, 256, 0, stream>>>(mask, mb);
  proj_gemm_k<<<dim3(16, 32), 256, 0, stream>>>(q, Wq, bq, Qb, nullptr, 0, qscale);
  proj_gemm_k<<<dim3(16, 32), 256, 0, stream>>>(k, Wk, bk, Kb, nullptr, 0, 1.0f);
  proj_gemm_k<<<dim3(16, 32), 256, 0, stream>>>(v, Wv, bv, nullptr, Vt, 1, 1.0f);
  attn_k<<<512, 256, 0, stream>>>(Qb, Kb, Vt, mb, out);
}

// Round 5
// 224.696 us; speedup vs baseline: 1.9153x; 1.0320x over previous
//
#include <hip/hip_runtime.h>

typedef __bf16 bf16;
typedef __bf16 bf16x8 __attribute__((ext_vector_type(8)));
typedef __bf16 bf16x4 __attribute__((ext_vector_type(4)));
typedef float f32x4 __attribute__((ext_vector_type(4)));

#define MFMA_BF16(A, B, C) __builtin_amdgcn_mfma_f32_16x16x32_bf16((A), (B), (C), 0, 0, 0)

#define EMB 1024
#define ODIM 2048
#define SEQ 2048
#define HEADS 16
#define HD 128

// ---------------- mask bit-pack: mask (1,S,S) int32 -> mb[q][kt] uint64 ----------------
__global__ __launch_bounds__(256) void build_maskbits_k(const int* __restrict__ mask,
                                                        unsigned long long* __restrict__ mb) {
  int w = blockIdx.x * 256 + threadIdx.x;  // 0..65535 : q*32 + chunk
  int q = w >> 5, c = w & 31;
  const int4* m4 = reinterpret_cast<const int4*>(mask + (size_t)q * SEQ + c * 64);
  unsigned long long bits = 0ull;
#pragma unroll
  for (int i = 0; i < 16; ++i) {
    int4 v = m4[i];
    if (v.x) bits |= 1ull << (i * 4 + 0);
    if (v.y) bits |= 1ull << (i * 4 + 1);
    if (v.z) bits |= 1ull << (i * 4 + 2);
    if (v.w) bits |= 1ull << (i * 4 + 3);
  }
  mb[w] = bits;
}

// ---------------- projection GEMM: out = relu(X (4096x1024) * W^T (2048x1024) + b)*oscale ----------------
__global__ __launch_bounds__(256) void proj_gemm_k(const float* __restrict__ X,
                                                   const float* __restrict__ W,
                                                   const float* __restrict__ bias,
                                                   bf16* __restrict__ outN,
                                                   bf16* __restrict__ outT,
                                                   int vmode, float oscale) {
  __shared__ union {
    struct { bf16 A[128][40]; bf16 B[128][40]; } s;  // +8 pad: 2-way conflicts max (free)
    bf16 C[128][136];                                // transpose buffer (epilogue only)
  } sm;

  const int t = threadIdx.x;
  const int lane = t & 63;
  const int wid = t >> 6;
  const int wm = wid >> 1, wn = wid & 1;
  const int lr = lane & 15, lg = lane >> 4;
  const int m0 = blockIdx.y * 128;
  const int n0 = blockIdx.x * 128;
  const int sr = t >> 1, sh = (t & 1) * 16;  // staging: 2 threads per row, 16 f32 each

  const f32x4 fzero = {0.f, 0.f, 0.f, 0.f};
  f32x4 acc[4][4];
#pragma unroll
  for (int i = 0; i < 4; ++i)
#pragma unroll
    for (int j = 0; j < 4; ++j) acc[i][j] = fzero;

  const float* Xr = X + (size_t)(m0 + sr) * EMB + sh;
  const float* Wr = W + (size_t)(n0 + sr) * EMB + sh;

  // async-split staging: issue tile k+1 loads while MFMAing tile k
  float4 ar[4], br[4];
  {
    const float4* pa = reinterpret_cast<const float4*>(Xr);
    const float4* pb = reinterpret_cast<const float4*>(Wr);
#pragma unroll
    for (int i = 0; i < 4; ++i) { ar[i] = pa[i]; br[i] = pb[i]; }
  }

  for (int k0 = 0; k0 < EMB; k0 += 32) {
    {
      bf16x8 v0, v1, w0, w1;
      v0[0] = (bf16)ar[0].x; v0[1] = (bf16)ar[0].y; v0[2] = (bf16)ar[0].z; v0[3] = (bf16)ar[0].w;
      v0[4] = (bf16)ar[1].x; v0[5] = (bf16)ar[1].y; v0[6] = (bf16)ar[1].z; v0[7] = (bf16)ar[1].w;
      v1[0] = (bf16)ar[2].x; v1[1] = (bf16)ar[2].y; v1[2] = (bf16)ar[2].z; v1[3] = (bf16)ar[2].w;
      v1[4] = (bf16)ar[3].x; v1[5] = (bf16)ar[3].y; v1[6] = (bf16)ar[3].z; v1[7] = (bf16)ar[3].w;
      w0[0] = (bf16)br[0].x; w0[1] = (bf16)br[0].y; w0[2] = (bf16)br[0].z; w0[3] = (bf16)br[0].w;
      w0[4] = (bf16)br[1].x; w0[5] = (bf16)br[1].y; w0[6] = (bf16)br[1].z; w0[7] = (bf16)br[1].w;
      w1[0] = (bf16)br[2].x; w1[1] = (bf16)br[2].y; w1[2] = (bf16)br[2].z; w1[3] = (bf16)br[2].w;
      w1[4] = (bf16)br[3].x; w1[5] = (bf16)br[3].y; w1[6] = (bf16)br[3].z; w1[7] = (bf16)br[3].w;
      *(bf16x8*)&sm.s.A[sr][sh] = v0;
      *(bf16x8*)&sm.s.A[sr][sh + 8] = v1;
      *(bf16x8*)&sm.s.B[sr][sh] = w0;
      *(bf16x8*)&sm.s.B[sr][sh + 8] = w1;
    }
    __syncthreads();
    if (k0 + 32 < EMB) {
      const float4* pa = reinterpret_cast<const float4*>(Xr + k0 + 32);
      const float4* pb = reinterpret_cast<const float4*>(Wr + k0 + 32);
#pragma unroll
      for (int i = 0; i < 4; ++i) { ar[i] = pa[i]; br[i] = pb[i]; }
    }
    bf16x8 af[4], bfr[4];
#pragma unroll
    for (int i = 0; i < 4; ++i) af[i] = *(const bf16x8*)&sm.s.A[wm * 64 + i * 16 + lr][lg * 8];
#pragma unroll
    for (int i = 0; i < 4; ++i) bfr[i] = *(const bf16x8*)&sm.s.B[wn * 64 + i * 16 + lr][lg * 8];
#pragma unroll
    for (int mi = 0; mi < 4; ++mi)
#pragma unroll
      for (int ni = 0; ni < 4; ++ni)
        acc[mi][ni] = MFMA_BF16(af[mi], bfr[ni], acc[mi][ni]);
    __syncthreads();
  }

  float bv_[4];
#pragma unroll
  for (int ni = 0; ni < 4; ++ni) bv_[ni] = bias[n0 + wn * 64 + ni * 16 + lr];

  if (!vmode) {
#pragma unroll
    for (int mi = 0; mi < 4; ++mi)
#pragma unroll
      for (int ni = 0; ni < 4; ++ni)
#pragma unroll
        for (int j = 0; j < 4; ++j) {
          float v = fmaxf(acc[mi][ni][j] + bv_[ni], 0.f) * oscale;
          int row = m0 + wm * 64 + mi * 16 + lg * 4 + j;
          int col = n0 + wn * 64 + ni * 16 + lr;
          outN[(size_t)row * ODIM + col] = (bf16)v;
        }
  } else {
    // transpose tile through LDS, then coalesced row writes into Vt[n][h][d][s]
#pragma unroll
    for (int mi = 0; mi < 4; ++mi)
#pragma unroll
      for (int ni = 0; ni < 4; ++ni)
#pragma unroll
        for (int j = 0; j < 4; ++j) {
          float v = fmaxf(acc[mi][ni][j] + bv_[ni], 0.f) * oscale;
          int rit = wm * 64 + mi * 16 + lg * 4 + j;  // s within tile
          int cit = wn * 64 + ni * 16 + lr;          // d within tile
          sm.C[cit][rit] = (bf16)v;
        }
    __syncthreads();
    const int n = m0 >> 11;
    const int s0 = m0 & (SEQ - 1);
    const int h = blockIdx.x;  // n0/128 == head (BN==HD)
    bf16* base = outT + ((size_t)(n * HEADS + h) * HD) * SEQ + s0;
#pragma unroll
    for (int i = 0; i < 8; ++i) {
      int cid = i * 256 + t;
      int d = cid >> 4, c = cid & 15;
      *(bf16x8*)(base + (size_t)d * SEQ + c * 8) = *(const bf16x8*)&sm.C[d][c * 8];
    }
  }
}

// ---------------- flash attention v5: log2-domain softmax, mask-as-acc-init, l-via-MFMA ----------------
// grid: 512 blocks XCD-swizzled; 256 threads = 4 waves; 32 q-rows/wave (two 16-col B frags).
// Q is pre-scaled by (1/sqrt(HD))*log2(e) -> softmax entirely in exp2 domain.
// Vs has a 145th..160th row band: row 128 = ones -> PV's df=8 accumulator IS the softmax
// denominator l (rescaled by alpha along with O automatically).

__device__ __forceinline__ int kswz(int r, int c) {  // bf16 index into Ks[64][128]
  int b = (r << 8) | (c << 1);
  b ^= (r & 7) << 4;
  return b >> 1;
}
__device__ __forceinline__ int vswz(int d, int s) {  // bf16 index into Vs[144][64]
  int b = (d << 7) | (s << 1);
  b ^= (d & 7) << 4;
  return b >> 1;
}

__global__ __launch_bounds__(256, 2) void attn_k(const bf16* __restrict__ Qb,
                                                 const bf16* __restrict__ Kb,
                                                 const bf16* __restrict__ Vt,
                                                 const unsigned long long* __restrict__ mb,
                                                 float* __restrict__ out) {
  __shared__ bf16 Ks[64 * 128];    // swizzled, 16 KB
  __shared__ bf16 Vs[144 * 64];    // swizzled, 18 KB (rows 128..143: ones-row band)
  __shared__ bf16 Ps[4][32][72];   // per-wave P: [q][k], +8 pad, 18 KB

  const int t = threadIdx.x;
  const int lane = t & 63;
  const int w = t >> 6;
  const int lr = lane & 15, lg = lane >> 4;

  const int bid = blockIdx.x;
  const int swz = (bid & 7) * 64 + (bid >> 3);  // bijective: 512 = 8*64; 4 heads per XCD
  const int nh = swz >> 4;
  const int qt = swz & 15;
  const int n = nh >> 4, h = nh & 15;
  const int qrow = qt * 128 + w * 32;

  // ones-row band for the l-accumulator (row 128 = 1.0, rows 129..143 = 0)
  {
    int d = 128 + (t >> 4), s4 = (t & 15) * 4;
    bf16 one = (bf16)1.0f, zero = (bf16)0.0f;
    bf16x4 v = {zero, zero, zero, zero};
    if (d == 128) { v[0] = one; v[1] = one; v[2] = one; v[3] = one; }
    *(bf16x4*)&Vs[vswz(d, s4)] = v;
  }

  // Q fragments (B-operand: col=q=lane&15, k=d). Q pre-scaled by qscale*log2e.
  bf16x8 qf[2][4];
#pragma unroll
  for (int g = 0; g < 2; ++g) {
    const bf16* qp = Qb + (size_t)(n * SEQ + qrow + g * 16 + lr) * ODIM + h * HD + lg * 8;
#pragma unroll
    for (int ks = 0; ks < 4; ++ks) qf[g][ks] = *(const bf16x8*)(qp + ks * 32);
  }

  const bf16* Kg = Kb + (size_t)(n * SEQ) * ODIM + h * HD;
  const bf16* Vg = Vt + (size_t)nh * HD * SEQ;

  // staging assignments (reg-staged, async-split)
  const int rK = t >> 4, cK = t & 15;  // K: 16 threads/row, 8 bf16 each
  const int dV = t >> 3, cV = t & 7;   // V^T: 8 threads/row
  const bf16* kgp = Kg + (size_t)rK * ODIM + cK * 8;
  const bf16* vgp = Vg + (size_t)dV * SEQ + cV * 8;

  bf16x8 kreg[4], vreg[4];
#pragma unroll
  for (int i = 0; i < 4; ++i) kreg[i] = *(const bf16x8*)(kgp + (size_t)i * 16 * ODIM);
#pragma unroll
  for (int i = 0; i < 4; ++i) vreg[i] = *(const bf16x8*)(vgp + (size_t)i * 32 * SEQ);

  f32x4 oacc[2][9];  // [g][0..7]=O^T frags; [g][8]=l accumulator (ones-row)
#pragma unroll
  for (int g = 0; g < 2; ++g)
#pragma unroll
    for (int i = 0; i < 9; ++i) oacc[g][i] = {0.f, 0.f, 0.f, 0.f};
  float mrun[2] = {-3.0e38f, -3.0e38f};

  for (int kt = 0; kt < SEQ / 64; ++kt) {
    // ---- write staged regs (tile kt) to swizzled LDS ----
#pragma unroll
    for (int i = 0; i < 4; ++i) *(bf16x8*)&Ks[kswz(rK + i * 16, cK * 8)] = kreg[i];
#pragma unroll
    for (int i = 0; i < 4; ++i) *(bf16x8*)&Vs[vswz(dV + i * 32, cV * 8)] = vreg[i];
    __syncthreads();

    // ---- issue tile kt+1 global loads (latency hides under compute below) ----
    if (kt + 1 < SEQ / 64) {
      const bf16* kn = kgp + (size_t)(kt + 1) * 64 * ODIM;
      const bf16* vn = vgp + (size_t)(kt + 1) * 64;
#pragma unroll
      for (int i = 0; i < 4; ++i) kreg[i] = *(const bf16x8*)(kn + (size_t)i * 16 * ODIM);
#pragma unroll
      for (int i = 0; i < 4; ++i) vreg[i] = *(const bf16x8*)(vn + (size_t)i * 32 * SEQ);
    }

    unsigned long long mw0 = mb[(size_t)(qrow + lr) * 32 + kt];
    unsigned long long mw1 = mb[(size_t)(qrow + 16 + lr) * 32 + kt];

    // ---- mask-as-accumulator-init (builds during MFMA shadow), then S^T = K Q^T ----
    f32x4 sacc[2][4];
#pragma unroll
    for (int f = 0; f < 4; ++f)
#pragma unroll
      for (int j = 0; j < 4; ++j) {
        int kk = f * 16 + lg * 4 + j;
        sacc[0][f][j] = ((mw0 >> kk) & 1ull) ? 0.f : -1.0e7f;
        sacc[1][f][j] = ((mw1 >> kk) & 1ull) ? 0.f : -1.0e7f;
      }
#pragma unroll
    for (int f = 0; f < 4; ++f) {
#pragma unroll
      for (int ks = 0; ks < 4; ++ks) {
        bf16x8 kf = *(const bf16x8*)&Ks[kswz(f * 16 + lr, ks * 32 + lg * 8)];
        sacc[0][f] = MFMA_BF16(kf, qf[0][ks], sacc[0][f]);
        sacc[1][f] = MFMA_BF16(kf, qf[1][ks], sacc[1][f]);
      }
    }

    // ---- lane-local online softmax in log2 domain ----
    float mt[2] = {-3.0e38f, -3.0e38f};
#pragma unroll
    for (int g = 0; g < 2; ++g) {
#pragma unroll
      for (int f = 0; f < 4; ++f) {
        float a = fmaxf(sacc[g][f][0], sacc[g][f][1]);
        float b = fmaxf(sacc[g][f][2], sacc[g][f][3]);
        mt[g] = fmaxf(mt[g], fmaxf(a, b));
      }
      mt[g] = fmaxf(mt[g], __shfl_xor(mt[g], 16));
      mt[g] = fmaxf(mt[g], __shfl_xor(mt[g], 32));
    }

    // defer-max (T13): rescale only when max moved by >8 (log2 units; P <= 256)
    if (!__all((mt[0] <= mrun[0] + 8.0f) && (mt[1] <= mrun[1] + 8.0f))) {
#pragma unroll
      for (int g = 0; g < 2; ++g) {
        float mnew = fmaxf(mrun[g], mt[g]);
        float alpha = exp2f(mrun[g] - mnew);
        mrun[g] = mnew;
#pragma unroll
        for (int df = 0; df < 9; ++df)  // df=8: l-acc rescales too
#pragma unroll
          for (int j = 0; j < 4; ++j) oacc[g][df][j] *= alpha;
      }
    }

    // ---- P = exp2(S - m); pack to per-wave LDS ----
#pragma unroll
    for (int g = 0; g < 2; ++g)
#pragma unroll
      for (int f = 0; f < 4; ++f) {
        bf16x4 pw;
#pragma unroll
        for (int j = 0; j < 4; ++j) pw[j] = (bf16)exp2f(sacc[g][f][j] - mrun[g]);
        *(bf16x4*)&Ps[w][g * 16 + lr][f * 16 + lg * 4] = pw;
      }

    bf16x8 pB[2][2];
#pragma unroll
    for (int g = 0; g < 2; ++g)
#pragma unroll
      for (int ks = 0; ks < 2; ++ks)
        pB[g][ks] = *(const bf16x8*)&Ps[w][g * 16 + lr][ks * 32 + lg * 8];

    // ---- O^T += V^T P (df=8 accumulates l via ones-row) ----
#pragma unroll
    for (int df = 0; df < 9; ++df) {
#pragma unroll
      for (int ks = 0; ks < 2; ++ks) {
        bf16x8 vf = *(const bf16x8*)&Vs[vswz(df * 16 + lr, ks * 32 + lg * 8)];
        oacc[0][df] = MFMA_BF16(vf, pB[0][ks], oacc[0][df]);
        oacc[1][df] = MFMA_BF16(vf, pB[1][ks], oacc[1][df]);
      }
    }
    __syncthreads();
  }

  // ---- epilogue: l lives at lane lr (lg=0), elem 0 of oacc[g][8] ----
#pragma unroll
  for (int g = 0; g < 2; ++g) {
    float l = __shfl(oacc[g][8][0], lr);
    float inv = 1.0f / l;
    float* obase = out + (size_t)(n * SEQ + qrow + g * 16 + lr) * ODIM + h * HD;
#pragma unroll
    for (int df = 0; df < 8; ++df) {
      f32x4 o;
#pragma unroll
      for (int j = 0; j < 4; ++j) o[j] = oacc[g][df][j] * inv;
      *(f32x4*)(obase + df * 16 + lg * 4) = o;
    }
  }
}

extern "C" void kernel_launch(void* const* d_in, const int* in_sizes, int n_in,
                              void* d_out, int out_size, void* d_ws, size_t ws_size,
                              hipStream_t stream) {
  const float* q   = (const float*)d_in[0];
  const float* k   = (const float*)d_in[1];
  const float* v   = (const float*)d_in[2];
  const int*  mask = (const int*)d_in[3];
  const float* Wq  = (const float*)d_in[4];
  const float* bq  = (const float*)d_in[5];
  const float* Wk  = (const float*)d_in[6];
  const float* bk  = (const float*)d_in[7];
  const float* Wv  = (const float*)d_in[8];
  const float* bv  = (const float*)d_in[9];
  float* out = (float*)d_out;

  char* ws = (char*)d_ws;
  const size_t PLANE = (size_t)4096 * 2048 * sizeof(bf16);  // 16 MiB
  bf16* Qb = (bf16*)ws;
  bf16* Kb = (bf16*)(ws + PLANE);
  bf16* Vt = (bf16*)(ws + 2 * PLANE);
  unsigned long long* mb = (unsigned long long*)(ws + 3 * PLANE);

  // 1/sqrt(128) * log2(e): softmax runs in exp2 domain
  const float qscale = 0.08838834764831845f * 1.4426950408889634f;

  build_maskbits_k<<<256, 256, 0, stream>>>(mask, mb);
  proj_gemm_k<<<dim3(16, 32), 256, 0, stream>>>(q, Wq, bq, Qb, nullptr, 0, qscale);
  proj_gemm_k<<<dim3(16, 32), 256, 0, stream>>>(k, Wk, bk, Kb, nullptr, 0, 1.0f);
  proj_gemm_k<<<dim3(16, 32), 256, 0, stream>>>(v, Wv, bv, nullptr, Vt, 1, 1.0f);
  attn_k<<<512, 256, 0, stream>>>(Qb, Kb, Vt, mb, out);
}

// Round 6
// 198.231 us; speedup vs baseline: 2.1710x; 1.1335x over previous
//
#include <hip/hip_runtime.h>

typedef __bf16 bf16;
typedef __bf16 bf16x8 __attribute__((ext_vector_type(8)));
typedef __bf16 bf16x4 __attribute__((ext_vector_type(4)));
typedef float f32x4 __attribute__((ext_vector_type(4)));

#define MFMA_BF16(A, B, C) __builtin_amdgcn_mfma_f32_16x16x32_bf16((A), (B), (C), 0, 0, 0)

#define EMB 1024
#define ODIM 2048
#define SEQ 2048
#define HEADS 16
#define HD 128

__device__ __forceinline__ void gload16(const bf16* g, const bf16* l) {
  __builtin_amdgcn_global_load_lds(
      (const __attribute__((address_space(1))) unsigned int*)(const void*)g,
      (__attribute__((address_space(3))) unsigned int*)(void*)l, 16, 0, 0);
}

// ---------------- prepass: f32 -> bf16 for q,k,v (3x4096x1024) and Wq,Wk,Wv (3x2048x1024) ----------------
__global__ __launch_bounds__(256) void cvt_bf16_k(const float* __restrict__ q,
                                                  const float* __restrict__ k,
                                                  const float* __restrict__ v,
                                                  const float* __restrict__ Wq,
                                                  const float* __restrict__ Wk,
                                                  const float* __restrict__ Wv,
                                                  bf16* __restrict__ Xall,
                                                  bf16* __restrict__ Wall) {
  const unsigned XV = 4096u * 1024u / 8u;  // 524288 vec8 per X plane
  const unsigned WV = 2048u * 1024u / 8u;  // 262144 vec8 per W plane
  unsigned id = blockIdx.x * 256 + threadIdx.x;
  const float* src;
  bf16* dst;
  size_t off;
  if (id < 3 * XV) {
    unsigned p = id / XV;
    off = (size_t)(id - p * XV) * 8;
    src = (p == 0) ? q : (p == 1 ? k : v);
    dst = Xall + (size_t)p * (4096u * 1024u);
  } else {
    unsigned id2 = id - 3 * XV;
    unsigned p = id2 / WV;
    off = (size_t)(id2 - p * WV) * 8;
    src = (p == 0) ? Wq : (p == 1 ? Wk : Wv);
    dst = Wall + (size_t)p * (2048u * 1024u);
  }
  float4 a = *(const float4*)(src + off);
  float4 b = *(const float4*)(src + off + 4);
  bf16x8 o;
  o[0] = (bf16)a.x; o[1] = (bf16)a.y; o[2] = (bf16)a.z; o[3] = (bf16)a.w;
  o[4] = (bf16)b.x; o[5] = (bf16)b.y; o[6] = (bf16)b.z; o[7] = (bf16)b.w;
  *(bf16x8*)(dst + off) = o;
}

// ---------------- mask bit-pack: mask (1,S,S) int32 -> mb[q][kt] uint64 ----------------
__global__ __launch_bounds__(256) void build_maskbits_k(const int* __restrict__ mask,
                                                        unsigned long long* __restrict__ mb) {
  int w = blockIdx.x * 256 + threadIdx.x;  // 0..65535 : q*32 + chunk
  int q = w >> 5, c = w & 31;
  const int4* m4 = reinterpret_cast<const int4*>(mask + (size_t)q * SEQ + c * 64);
  unsigned long long bits = 0ull;
#pragma unroll
  for (int i = 0; i < 16; ++i) {
    int4 v = m4[i];
    if (v.x) bits |= 1ull << (i * 4 + 0);
    if (v.y) bits |= 1ull << (i * 4 + 1);
    if (v.z) bits |= 1ull << (i * 4 + 2);
    if (v.w) bits |= 1ull << (i * 4 + 3);
  }
  mb[w] = bits;
}

// ---------------- projection GEMMs (merged z=0,1,2): relu(X W^T + b)*oscale ----------------
// bf16 inputs; global_load_lds staging into XOR-swizzled LDS (linear dest + pre-swizzled src).
// z==0 -> Qb (row-major, scaled by qscale), z==1 -> Kb, z==2 -> Vt (per-head transposed)
__global__ __launch_bounds__(256) void proj_gemm_k(const bf16* __restrict__ Xall,
                                                   const bf16* __restrict__ Wall,
                                                   const float* __restrict__ bq,
                                                   const float* __restrict__ bk_,
                                                   const float* __restrict__ bv_,
                                                   bf16* __restrict__ Qb,
                                                   bf16* __restrict__ Kb,
                                                   bf16* __restrict__ Vt,
                                                   float qscale) {
  __shared__ union {
    struct { bf16 A[128 * 64]; bf16 B[128 * 64]; } s;  // swizzled storage, 32 KB
    bf16 C[128][136];                                  // transpose buffer (epilogue only)
  } sm;

  const int t = threadIdx.x;
  const int lane = t & 63;
  const int wid = t >> 6;
  const int wm = wid >> 1, wn = wid & 1;
  const int lr = lane & 15, lg = lane >> 4;
  const int z = blockIdx.z;
  const int m0 = blockIdx.y * 128;
  const int n0 = blockIdx.x * 128;
  const bf16* X = Xall + (size_t)z * (4096u * 1024u);
  const bf16* W = Wall + (size_t)z * (2048u * 1024u);
  const float* bias = (z == 0) ? bq : (z == 1 ? bk_ : bv_);
  const float oscale = (z == 0) ? qscale : 1.0f;

  const int sr_ = t >> 3;        // staging row within 32-row call group
  const int scb = (t & 7) * 16;  // staging byte col (pre-swizzle)

  f32x4 acc[4][4];
#pragma unroll
  for (int i = 0; i < 4; ++i)
#pragma unroll
    for (int j = 0; j < 4; ++j) acc[i][j] = {0.f, 0.f, 0.f, 0.f};

  for (int k0 = 0; k0 < EMB; k0 += 64) {
    // stage A then B: linear LDS dest (t*16B), source address carries the inverse swizzle
#pragma unroll
    for (int j = 0; j < 4; ++j) {
      int r = j * 32 + sr_;
      int cb = scb ^ ((r & 7) << 4);
      gload16(X + (size_t)(m0 + r) * EMB + k0 + (cb >> 1), &sm.s.A[j * 2048 + t * 8]);
    }
#pragma unroll
    for (int j = 0; j < 4; ++j) {
      int r = j * 32 + sr_;
      int cb = scb ^ ((r & 7) << 4);
      gload16(W + (size_t)(n0 + r) * EMB + k0 + (cb >> 1), &sm.s.B[j * 2048 + t * 8]);
    }
    __syncthreads();

    bf16x8 af[4][2], bfr[4][2];
#pragma unroll
    for (int i = 0; i < 4; ++i)
#pragma unroll
      for (int s = 0; s < 2; ++s) {
        int ra = wm * 64 + i * 16 + lr;
        int ca = (s * 64 + lg * 16) ^ ((ra & 7) << 4);  // byte within row
        af[i][s] = *(const bf16x8*)&sm.s.A[ra * 64 + (ca >> 1)];
        int rb = wn * 64 + i * 16 + lr;
        int cb2 = (s * 64 + lg * 16) ^ ((rb & 7) << 4);
        bfr[i][s] = *(const bf16x8*)&sm.s.B[rb * 64 + (cb2 >> 1)];
      }
#pragma unroll
    for (int s = 0; s < 2; ++s)
#pragma unroll
      for (int mi = 0; mi < 4; ++mi)
#pragma unroll
        for (int ni = 0; ni < 4; ++ni)
          acc[mi][ni] = MFMA_BF16(af[mi][s], bfr[ni][s], acc[mi][ni]);
    __syncthreads();
  }

  float bv4[4];
#pragma unroll
  for (int ni = 0; ni < 4; ++ni) bv4[ni] = bias[n0 + wn * 64 + ni * 16 + lr];

  if (z < 2) {
    bf16* outN = (z == 0) ? Qb : Kb;
#pragma unroll
    for (int mi = 0; mi < 4; ++mi)
#pragma unroll
      for (int ni = 0; ni < 4; ++ni)
#pragma unroll
        for (int j = 0; j < 4; ++j) {
          float v = fmaxf(acc[mi][ni][j] + bv4[ni], 0.f) * oscale;
          int row = m0 + wm * 64 + mi * 16 + lg * 4 + j;
          int col = n0 + wn * 64 + ni * 16 + lr;
          outN[(size_t)row * ODIM + col] = (bf16)v;
        }
  } else {
    // transpose tile through LDS, then coalesced row writes into Vt[n][h][d][s]
#pragma unroll
    for (int mi = 0; mi < 4; ++mi)
#pragma unroll
      for (int ni = 0; ni < 4; ++ni)
#pragma unroll
        for (int j = 0; j < 4; ++j) {
          float v = fmaxf(acc[mi][ni][j] + bv4[ni], 0.f);
          int rit = wm * 64 + mi * 16 + lg * 4 + j;  // s within tile
          int cit = wn * 64 + ni * 16 + lr;          // d within tile
          sm.C[cit][rit] = (bf16)v;
        }
    __syncthreads();
    const int n = m0 >> 11;
    const int s0 = m0 & (SEQ - 1);
    const int h = blockIdx.x;  // BN==HD
    bf16* base = Vt + ((size_t)(n * HEADS + h) * HD) * SEQ + s0;
#pragma unroll
    for (int i = 0; i < 8; ++i) {
      int cid = i * 256 + t;
      int d = cid >> 4, c = cid & 15;
      *(bf16x8*)(base + (size_t)d * SEQ + c * 8) = *(const bf16x8*)&sm.C[d][c * 8];
    }
  }
}

// ---------------- flash attention v6: 8-wave block, K/V double-buffer, 1 barrier/tile ----------------
// 256 blocks (1/CU), 512 threads = 8 waves, 32 q-rows/wave (two 16-col B frags), 256 q/block.
// QK^T as mfma(K,Q) -> S^T (lane-local softmax, log2 domain); PV as mfma(V^T,P) -> O^T.
// l-denominator via register ones-A-fragment MFMA (no LDS band).

__device__ __forceinline__ int kswz(int r, int c) {  // bf16 idx into one Ks buf [64][128]
  int b = (r << 8) | (c << 1);
  b ^= (r & 7) << 4;
  return b >> 1;
}
__device__ __forceinline__ int vswz(int d, int s) {  // bf16 idx into one Vs buf [128][64]
  int b = (d << 7) | (s << 1);
  b ^= (d & 7) << 4;
  return b >> 1;
}

__global__ __launch_bounds__(512, 2) void attn_k(const bf16* __restrict__ Qb,
                                                 const bf16* __restrict__ Kb,
                                                 const bf16* __restrict__ Vt,
                                                 const unsigned long long* __restrict__ mb,
                                                 float* __restrict__ out) {
  __shared__ bf16 Ks[2][64 * 128];  // 2 x 16 KB
  __shared__ bf16 Vs[2][128 * 64];  // 2 x 16 KB
  __shared__ bf16 Ps[8][32][72];    // per-wave P, 36 KB

  const int t = threadIdx.x;
  const int lane = t & 63;
  const int w = t >> 6;
  const int lr = lane & 15, lg = lane >> 4;

  const int bid = blockIdx.x;
  const int swz = (bid & 7) * 32 + (bid >> 3);  // bijective: 256 = 8*32; 4 heads per XCD
  const int nh = swz >> 3;
  const int qt = swz & 7;
  const int n = nh >> 4, h = nh & 15;
  const int qrow = qt * 256 + w * 32;

  // Q fragments (B-operand: col=q=lane&15, k=d). Q pre-scaled by (1/sqrt(HD))*log2(e).
  bf16x8 qf[2][4];
#pragma unroll
  for (int g = 0; g < 2; ++g) {
    const bf16* qp = Qb + (size_t)(n * SEQ + qrow + g * 16 + lr) * ODIM + h * HD + lg * 8;
#pragma unroll
    for (int ks = 0; ks < 4; ++ks) qf[g][ks] = *(const bf16x8*)(qp + ks * 32);
  }

  // ones A-fragment: virtual row 0 = 1.0 -> accumulates l = sum_k P[k][q]
  bf16x8 onesA;
  {
    bf16 o1 = (bf16)((lr == 0) ? 1.0f : 0.0f);
#pragma unroll
    for (int j = 0; j < 8; ++j) onesA[j] = o1;
  }

  const bf16* Kg = Kb + (size_t)(n * SEQ) * ODIM + h * HD;
  const bf16* Vg = Vt + (size_t)nh * HD * SEQ;

  // staging (512 threads): K 64x128 -> 2 x bf16x8/thread; V^T 128x64 -> 2 x bf16x8/thread
  const int rK = t >> 4, cK = t & 15;  // rK 0..31 (rows rK, rK+32)
  const int dV = t >> 3, cV = t & 7;   // dV 0..63 (rows dV, dV+64)
  const bf16* kgp = Kg + (size_t)rK * ODIM + cK * 8;
  const bf16* vgp = Vg + (size_t)dV * SEQ + cV * 8;

  bf16x8 kreg[2], vreg[2];
#pragma unroll
  for (int i = 0; i < 2; ++i) kreg[i] = *(const bf16x8*)(kgp + (size_t)i * 32 * ODIM);
#pragma unroll
  for (int i = 0; i < 2; ++i) vreg[i] = *(const bf16x8*)(vgp + (size_t)i * 64 * SEQ);
#pragma unroll
  for (int i = 0; i < 2; ++i) *(bf16x8*)&Ks[0][kswz(rK + i * 32, cK * 8)] = kreg[i];
#pragma unroll
  for (int i = 0; i < 2; ++i) *(bf16x8*)&Vs[0][vswz(dV + i * 64, cV * 8)] = vreg[i];
  __syncthreads();

  f32x4 oacc[2][9];  // [g][0..7]=O^T frags; [g][8]=l accumulator
#pragma unroll
  for (int g = 0; g < 2; ++g)
#pragma unroll
    for (int i = 0; i < 9; ++i) oacc[g][i] = {0.f, 0.f, 0.f, 0.f};
  float mrun[2] = {-3.0e38f, -3.0e38f};

  const int NT = SEQ / 64;
  for (int kt = 0; kt < NT; ++kt) {
    const int cur = kt & 1;

    // ---- issue tile kt+1 global loads early (hide under QK+softmax) ----
    if (kt + 1 < NT) {
      const bf16* kn = kgp + (size_t)(kt + 1) * 64 * ODIM;
      const bf16* vn = vgp + (size_t)(kt + 1) * 64;
#pragma unroll
      for (int i = 0; i < 2; ++i) kreg[i] = *(const bf16x8*)(kn + (size_t)i * 32 * ODIM);
#pragma unroll
      for (int i = 0; i < 2; ++i) vreg[i] = *(const bf16x8*)(vn + (size_t)i * 64 * SEQ);
    }

    unsigned long long mw0 = mb[(size_t)(qrow + lr) * 32 + kt];
    unsigned long long mw1 = mb[(size_t)(qrow + 16 + lr) * 32 + kt];

    // ---- mask-as-accumulator-init, then S^T = K Q^T from Ks[cur] ----
    f32x4 sacc[2][4];
#pragma unroll
    for (int f = 0; f < 4; ++f)
#pragma unroll
      for (int j = 0; j < 4; ++j) {
        int kk = f * 16 + lg * 4 + j;
        sacc[0][f][j] = ((mw0 >> kk) & 1ull) ? 0.f : -1.0e7f;
        sacc[1][f][j] = ((mw1 >> kk) & 1ull) ? 0.f : -1.0e7f;
      }
#pragma unroll
    for (int f = 0; f < 4; ++f) {
#pragma unroll
      for (int ks = 0; ks < 4; ++ks) {
        bf16x8 kf = *(const bf16x8*)&Ks[cur][kswz(f * 16 + lr, ks * 32 + lg * 8)];
        sacc[0][f] = MFMA_BF16(kf, qf[0][ks], sacc[0][f]);
        sacc[1][f] = MFMA_BF16(kf, qf[1][ks], sacc[1][f]);
      }
    }

    // ---- lane-local online softmax (log2 domain) ----
    float mt[2] = {-3.0e38f, -3.0e38f};
#pragma unroll
    for (int g = 0; g < 2; ++g) {
#pragma unroll
      for (int f = 0; f < 4; ++f) {
        float a = fmaxf(sacc[g][f][0], sacc[g][f][1]);
        float b = fmaxf(sacc[g][f][2], sacc[g][f][3]);
        mt[g] = fmaxf(mt[g], fmaxf(a, b));
      }
      mt[g] = fmaxf(mt[g], __shfl_xor(mt[g], 16));
      mt[g] = fmaxf(mt[g], __shfl_xor(mt[g], 32));
    }

    // defer-max (T13): rescale only when max moved by >8 (log2 units; P <= 256)
    if (!__all((mt[0] <= mrun[0] + 8.0f) && (mt[1] <= mrun[1] + 8.0f))) {
#pragma unroll
      for (int g = 0; g < 2; ++g) {
        float mnew = fmaxf(mrun[g], mt[g]);
        float alpha = exp2f(mrun[g] - mnew);
        mrun[g] = mnew;
#pragma unroll
        for (int df = 0; df < 9; ++df)
#pragma unroll
          for (int j = 0; j < 4; ++j) oacc[g][df][j] *= alpha;
      }
    }

    // ---- P = exp2(S - m) -> per-wave LDS ----
#pragma unroll
    for (int g = 0; g < 2; ++g)
#pragma unroll
      for (int f = 0; f < 4; ++f) {
        bf16x4 pw;
#pragma unroll
        for (int j = 0; j < 4; ++j) pw[j] = (bf16)exp2f(sacc[g][f][j] - mrun[g]);
        *(bf16x4*)&Ps[w][g * 16 + lr][f * 16 + lg * 4] = pw;
      }

    // ---- write staged regs for tile kt+1 into the idle buffer ----
    if (kt + 1 < NT) {
#pragma unroll
      for (int i = 0; i < 2; ++i) *(bf16x8*)&Ks[cur ^ 1][kswz(rK + i * 32, cK * 8)] = kreg[i];
#pragma unroll
      for (int i = 0; i < 2; ++i) *(bf16x8*)&Vs[cur ^ 1][vswz(dV + i * 64, cV * 8)] = vreg[i];
    }

    bf16x8 pB[2][2];
#pragma unroll
    for (int g = 0; g < 2; ++g)
#pragma unroll
      for (int ks = 0; ks < 2; ++ks)
        pB[g][ks] = *(const bf16x8*)&Ps[w][g * 16 + lr][ks * 32 + lg * 8];

    // ---- O^T += V^T P from Vs[cur]; df=8 (l) via register ones fragment ----
#pragma unroll
    for (int df = 0; df < 8; ++df) {
#pragma unroll
      for (int ks = 0; ks < 2; ++ks) {
        bf16x8 vf = *(const bf16x8*)&Vs[cur][vswz(df * 16 + lr, ks * 32 + lg * 8)];
        oacc[0][df] = MFMA_BF16(vf, pB[0][ks], oacc[0][df]);
        oacc[1][df] = MFMA_BF16(vf, pB[1][ks], oacc[1][df]);
      }
    }
#pragma unroll
    for (int ks = 0; ks < 2; ++ks) {
      oacc[0][8] = MFMA_BF16(onesA, pB[0][ks], oacc[0][8]);
      oacc[1][8] = MFMA_BF16(onesA, pB[1][ks], oacc[1][8]);
    }
    __syncthreads();
  }

  // ---- epilogue: l at (lg=0, j=0, col=lr); O /= l; float4 stores ----
#pragma unroll
  for (int g = 0; g < 2; ++g) {
    float l = __shfl(oacc[g][8][0], lr);
    float inv = 1.0f / l;
    float* obase = out + (size_t)(n * SEQ + qrow + g * 16 + lr) * ODIM + h * HD;
#pragma unroll
    for (int df = 0; df < 8; ++df) {
      f32x4 o;
#pragma unroll
      for (int j = 0; j < 4; ++j) o[j] = oacc[g][df][j] * inv;
      *(f32x4*)(obase + df * 16 + lg * 4) = o;
    }
  }
}

extern "C" void kernel_launch(void* const* d_in, const int* in_sizes, int n_in,
                              void* d_out, int out_size, void* d_ws, size_t ws_size,
                              hipStream_t stream) {
  const float* q   = (const float*)d_in[0];
  const float* k   = (const float*)d_in[1];
  const float* v   = (const float*)d_in[2];
  const int*  mask = (const int*)d_in[3];
  const float* Wq  = (const float*)d_in[4];
  const float* bq  = (const float*)d_in[5];
  const float* Wk  = (const float*)d_in[6];
  const float* bk  = (const float*)d_in[7];
  const float* Wv  = (const float*)d_in[8];
  const float* bv  = (const float*)d_in[9];
  float* out = (float*)d_out;

  char* ws = (char*)d_ws;
  const size_t PLANE = (size_t)4096 * 2048 * sizeof(bf16);  // 16 MiB
  bf16* Qb = (bf16*)ws;
  bf16* Kb = (bf16*)(ws + PLANE);
  bf16* Vt = (bf16*)(ws + 2 * PLANE);
  unsigned long long* mb = (unsigned long long*)(ws + 3 * PLANE);            // 4 MiB
  bf16* Xall = (bf16*)(ws + 3 * PLANE + (4u << 20));                         // 24 MiB
  bf16* Wall = (bf16*)(ws + 3 * PLANE + (4u << 20) + (size_t)3 * 4096 * 1024 * 2);  // 12 MiB

  // 1/sqrt(128) * log2(e): softmax runs in exp2 domain
  const float qscale = 0.08838834764831845f * 1.4426950408889634f;

  cvt_bf16_k<<<9216, 256, 0, stream>>>(q, k, v, Wq, Wk, Wv, Xall, Wall);
  build_maskbits_k<<<256, 256, 0, stream>>>(mask, mb);
  proj_gemm_k<<<dim3(16, 32, 3), 256, 0, stream>>>(Xall, Wall, bq, bk, bv, Qb, Kb, Vt, qscale);
  attn_k<<<256, 512, 0, stream>>>(Qb, Kb, Vt, mb, out);
}